// Round 2
// baseline (1027.559 us; speedup 1.0000x reference)
//
#include <hip/hip_runtime.h>
#include <math.h>

// TiSASRec forward on MI355X — round 1: fused LN+QKV and addLN+FFN (8 launches).
// B=32, L=200, D=64, H=2, dh=32, NL=2.
#define BB 32
#define LLEN 200
#define DD 64
#define HH 2
#define DHH 32
#define NLAYER 2
#define BLD (BB * LLEN * DD)

// float(-2**32+1) rounds to -4294967296.0f in f32 (same as JAX's cast)
#define NEGV (-4294967296.0f)

__device__ inline float waveSum(float v) {
#pragma unroll
    for (int off = 32; off > 0; off >>= 1) v += __shfl_xor(v, off);
    return v;
}
__device__ inline float waveMax(float v) {
#pragma unroll
    for (int off = 32; off > 0; off >>= 1) v = fmaxf(v, __shfl_xor(v, off));
    return v;
}

// x[b,l,:] = item_emb[log_ids[b,l]] * sqrt(D) * keep
__global__ void embed_kernel(const int* __restrict__ log_ids,
                             const float* __restrict__ item_emb,
                             float* __restrict__ x) {
    int row = blockIdx.x;        // b*L + l
    int d = threadIdx.x;         // 0..63
    int id = log_ids[row];
    float v = item_emb[id * DD + d] * 8.0f;  // sqrt(64) = 8
    x[row * DD + d] = (id == 0) ? 0.0f : v;
}

// Fused: q = LN(x)*g+b (written to global for later residual), then
// Q = q@Wq^T+bq ; K = x@Wk^T+bk ; V = x@Wv^T+bv.  One wave (64 thr) per row.
__global__ void ln_qkv_kernel(const float* __restrict__ x,
                              const float* __restrict__ g,
                              const float* __restrict__ bln,
                              const float* __restrict__ Wq, const float* __restrict__ bq,
                              const float* __restrict__ Wk, const float* __restrict__ bk,
                              const float* __restrict__ Wv, const float* __restrict__ bv,
                              float* __restrict__ q,
                              float* __restrict__ Q, float* __restrict__ K,
                              float* __restrict__ V) {
    __shared__ float qs[DD], xs[DD];
    int row = blockIdx.x;
    int d = threadIdx.x;
    float xv = x[row * DD + d];
    xs[d] = xv;
    float m = waveSum(xv) * (1.0f / 64.0f);
    float c = xv - m;
    float var = waveSum(c * c) * (1.0f / 64.0f);
    float qv = (c / sqrtf(var + 1e-8f)) * g[d] + bln[d];
    qs[d] = qv;
    q[row * DD + d] = qv;
    __syncthreads();
    float aq = bq[d], ak = bk[d], av = bv[d];
#pragma unroll 8
    for (int j = 0; j < DD; ++j) {
        aq += qs[j] * Wq[d * DD + j];
        ak += xs[j] * Wk[d * DD + j];
        av += xs[j] * Wv[d * DD + j];
    }
    Q[row * DD + d] = aq;
    K[row * DD + d] = ak;
    V[row * DD + d] = av;
}

// Attention for one (b, q) row. 256 threads.
// Scores fold the three terms: s = Qh . (Kh + pKh + tKh(tmat)) / sqrt(dh)
// Output folds:               out = sum_k A * (Vh + pVh + tVh(tmat))
__global__ void attn_kernel(const float* __restrict__ Q,
                            const float* __restrict__ K,
                            const float* __restrict__ V,
                            const int* __restrict__ log_ids,
                            const int* __restrict__ log_times,
                            const float* __restrict__ posK,
                            const float* __restrict__ posV,
                            const float* __restrict__ tK_emb,
                            const float* __restrict__ tV_emb,
                            float* __restrict__ out) {
    __shared__ float Qs[DD];
    __shared__ float sc[HH][LLEN];
    __shared__ int tm[LLEN];
    __shared__ float outred[4][DD];

    int b = blockIdx.x / LLEN;
    int qi = blockIdx.x % LLEN;
    int tid = threadIdx.x;
    int row = b * LLEN + qi;

    if (tid < DD) Qs[tid] = Q[row * DD + tid];
    __syncthreads();

    bool padq = (log_ids[row] == 0);
    int tq = log_times[row];

    // phase 1: scores for each key k
    for (int k = tid; k < LLEN; k += 256) {
        int tk = log_times[b * LLEN + k];
        int dt = tq - tk;
        if (dt < 0) dt = -dt;
        float dtf = (float)dt / 86400.0f;
        dtf = fminf(dtf, 365.0f);
        int bucket = (int)dtf;   // trunc toward zero, matches astype(int32)
        tm[k] = bucket;
        const float* Kr = &K[(b * LLEN + k) * DD];
        const float* pKr = &posK[k * DD];
        const float* tKr = &tK_emb[bucket * DD];
        float s0 = 0.0f, s1 = 0.0f;
#pragma unroll 8
        for (int d = 0; d < DHH; ++d) {
            s0 += Qs[d] * (Kr[d] + pKr[d] + tKr[d]);
            s1 += Qs[DHH + d] * (Kr[DHH + d] + pKr[DHH + d] + tKr[DHH + d]);
        }
        s0 /= 5.656854249492381f;  // sqrt(32)
        s1 /= 5.656854249492381f;
        if (padq || k > qi) { s0 = NEGV; s1 = NEGV; }
        sc[0][k] = s0;
        sc[1][k] = s1;
    }
    __syncthreads();

    // phase 2: softmax — wave 0 handles head 0, wave 1 handles head 1
    int wid = tid >> 6, lane = tid & 63;
    if (wid < HH) {
        float m = -INFINITY;
        for (int k = lane; k < LLEN; k += 64) m = fmaxf(m, sc[wid][k]);
        m = waveMax(m);
        float psum = 0.0f;
        for (int k = lane; k < LLEN; k += 64) {
            float e = expf(sc[wid][k] - m);
            sc[wid][k] = e;
            psum += e;
        }
        float ssum = waveSum(psum);
        for (int k = lane; k < LLEN; k += 64) sc[wid][k] /= ssum;
    }
    __syncthreads();

    // phase 3: out[od] = sum_k A[h,k] * (V + posV + tV)[k, od]
    int od = tid & 63;
    int slice = tid >> 6;          // 0..3
    int h = od >> 5;               // head from output dim
    float acc = 0.0f;
    for (int k = slice; k < LLEN; k += 4) {
        float a = sc[h][k];
        int bucket = tm[k];
        acc += a * (V[(b * LLEN + k) * DD + od] + posV[k * DD + od] +
                    tV_emb[bucket * DD + od]);
    }
    outred[slice][od] = acc;
    __syncthreads();
    if (tid < DD) {
        float r = outred[0][tid] + outred[1][tid] + outred[2][tid] + outred[3][tid];
        out[row * DD + tid] = r;
    }
}

// Fused: x = LN(q+att)*g+b ; x = (x + relu(x@W1^T+b1)@W2^T + b2) * keep
__global__ void addln_ffn_kernel(const float* __restrict__ qin,
                                 const float* __restrict__ att,
                                 const float* __restrict__ g,
                                 const float* __restrict__ bln,
                                 const float* __restrict__ W1, const float* __restrict__ b1,
                                 const float* __restrict__ W2, const float* __restrict__ b2,
                                 const int* __restrict__ log_ids,
                                 float* __restrict__ xout) {
    __shared__ float xs[DD], hs[DD];
    int row = blockIdx.x;
    int d = threadIdx.x;
    float v = qin[row * DD + d] + att[row * DD + d];
    float m = waveSum(v) * (1.0f / 64.0f);
    float c = v - m;
    float var = waveSum(c * c) * (1.0f / 64.0f);
    float xv = (c / sqrtf(var + 1e-8f)) * g[d] + bln[d];
    xs[d] = xv;
    __syncthreads();
    float a = b1[d];
#pragma unroll 8
    for (int j = 0; j < DD; ++j) a += xs[j] * W1[d * DD + j];
    hs[d] = fmaxf(a, 0.0f);
    __syncthreads();
    float o = b2[d];
#pragma unroll 8
    for (int j = 0; j < DD; ++j) o += hs[j] * W2[d * DD + j];
    float res = xv + o;
    if (log_ids[row] == 0) res = 0.0f;
    xout[row * DD + d] = res;
}

// feats = LN(x)*g+b ; pos/neg logits = dot(feats, item_emb[ids])
__global__ void final_kernel(const float* __restrict__ x,
                             const float* __restrict__ g,
                             const float* __restrict__ b,
                             const float* __restrict__ item_emb,
                             const int* __restrict__ pos_ids,
                             const int* __restrict__ neg_ids,
                             float* __restrict__ out) {
    int row = blockIdx.x;
    int d = threadIdx.x;
    float v = x[row * DD + d];
    float m = waveSum(v) * (1.0f / 64.0f);
    float c = v - m;
    float var = waveSum(c * c) * (1.0f / 64.0f);
    float f = (c / sqrtf(var + 1e-8f)) * g[d] + b[d];
    int pid = pos_ids[row];
    int nid = neg_ids[row];
    float p = waveSum(f * item_emb[pid * DD + d]);
    float n = waveSum(f * item_emb[nid * DD + d]);
    if (d == 0) {
        out[row] = p;
        out[BB * LLEN + row] = n;
    }
}

extern "C" void kernel_launch(void* const* d_in, const int* in_sizes, int n_in,
                              void* d_out, int out_size, void* d_ws, size_t ws_size,
                              hipStream_t stream) {
    const int* log_ids = (const int*)d_in[0];
    const int* log_times = (const int*)d_in[1];
    const int* pos_ids = (const int*)d_in[2];
    const int* neg_ids = (const int*)d_in[3];
    const float* item_emb = (const float*)d_in[4];
    const float* posK = (const float*)d_in[5];
    const float* posV = (const float*)d_in[6];
    const float* tK_emb = (const float*)d_in[7];
    const float* tV_emb = (const float*)d_in[8];
    const float* ln1_g = (const float*)d_in[9];
    const float* ln1_b = (const float*)d_in[10];
    const float* Wq = (const float*)d_in[11];
    const float* bq = (const float*)d_in[12];
    const float* Wk = (const float*)d_in[13];
    const float* bk = (const float*)d_in[14];
    const float* Wv = (const float*)d_in[15];
    const float* bv = (const float*)d_in[16];
    const float* ln2_g = (const float*)d_in[17];
    const float* ln2_b = (const float*)d_in[18];
    const float* W1 = (const float*)d_in[19];
    const float* b1 = (const float*)d_in[20];
    const float* W2 = (const float*)d_in[21];
    const float* b2 = (const float*)d_in[22];
    const float* lnf_g = (const float*)d_in[23];
    const float* lnf_b = (const float*)d_in[24];

    float* ws = (float*)d_ws;
    float* x = ws;                 // [B,L,D]
    float* q = x + BLD;            // ln1 output (kept for residual)
    float* Qb = q + BLD;
    float* Kb = Qb + BLD;
    float* Vb = Kb + BLD;
    float* att = Vb + BLD;

    const int nrow = BB * LLEN;    // 6400

    embed_kernel<<<nrow, DD, 0, stream>>>(log_ids, item_emb, x);

    for (int i = 0; i < NLAYER; ++i) {
        ln_qkv_kernel<<<nrow, DD, 0, stream>>>(x, ln1_g + i * DD, ln1_b + i * DD,
                                               Wq + i * DD * DD, bq + i * DD,
                                               Wk + i * DD * DD, bk + i * DD,
                                               Wv + i * DD * DD, bv + i * DD,
                                               q, Qb, Kb, Vb);
        attn_kernel<<<nrow, 256, 0, stream>>>(Qb, Kb, Vb, log_ids, log_times,
                                              posK, posV, tK_emb, tV_emb, att);
        addln_ffn_kernel<<<nrow, DD, 0, stream>>>(q, att, ln2_g + i * DD,
                                                  ln2_b + i * DD,
                                                  W1 + i * DD * DD, b1 + i * DD,
                                                  W2 + i * DD * DD, b2 + i * DD,
                                                  log_ids, x);
    }

    final_kernel<<<nrow, DD, 0, stream>>>(x, lnf_g, lnf_b, item_emb,
                                          pos_ids, neg_ids, (float*)d_out);
}

// Round 3
// 376.717 us; speedup vs baseline: 2.7277x; 2.7277x over previous
//
#include <hip/hip_runtime.h>
#include <math.h>

// TiSASRec forward on MI355X — round 2: wave-per-query attention, coalesced
// row loads, posK/posV folded into K/V at projection time.
// B=32, L=200, D=64, H=2, dh=32, NL=2.
#define BB 32
#define LLEN 200
#define DD 64
#define HH 2
#define DHH 32
#define NLAYER 2
#define BLD (BB * LLEN * DD)

// float(-2**32+1) rounds to -4294967296.0f in f32 (same as JAX's cast)
#define NEGV (-4294967296.0f)

__device__ inline float waveSum(float v) {
#pragma unroll
    for (int off = 32; off > 0; off >>= 1) v += __shfl_xor(v, off);
    return v;
}

// sum within each 32-lane half (head-local reduce)
__device__ inline float halfSum(float v) {
    v += __shfl_xor(v, 1);
    v += __shfl_xor(v, 2);
    v += __shfl_xor(v, 4);
    v += __shfl_xor(v, 8);
    v += __shfl_xor(v, 16);
    return v;
}
__device__ inline float halfMax(float v) {
    v = fmaxf(v, __shfl_xor(v, 1));
    v = fmaxf(v, __shfl_xor(v, 2));
    v = fmaxf(v, __shfl_xor(v, 4));
    v = fmaxf(v, __shfl_xor(v, 8));
    v = fmaxf(v, __shfl_xor(v, 16));
    return v;
}

// x[b,l,:] = item_emb[log_ids[b,l]] * sqrt(D) * keep
__global__ void embed_kernel(const int* __restrict__ log_ids,
                             const float* __restrict__ item_emb,
                             float* __restrict__ x) {
    int row = blockIdx.x;        // b*L + l
    int d = threadIdx.x;         // 0..63
    int id = log_ids[row];
    float v = item_emb[id * DD + d] * 8.0f;  // sqrt(64) = 8
    x[row * DD + d] = (id == 0) ? 0.0f : v;
}

// Fused: q = LN(x)*g+b (kept for residual), then
// Q = q@Wq^T+bq ; K_eff = x@Wk^T+bk+posK[l] ; V_eff = x@Wv^T+bv+posV[l].
__global__ void ln_qkv_kernel(const float* __restrict__ x,
                              const float* __restrict__ g,
                              const float* __restrict__ bln,
                              const float* __restrict__ Wq, const float* __restrict__ bq,
                              const float* __restrict__ Wk, const float* __restrict__ bk,
                              const float* __restrict__ Wv, const float* __restrict__ bv,
                              const float* __restrict__ posK,
                              const float* __restrict__ posV,
                              float* __restrict__ q,
                              float* __restrict__ Q, float* __restrict__ K,
                              float* __restrict__ V) {
    __shared__ float qs[DD], xs[DD];
    int row = blockIdx.x;
    int l = row % LLEN;
    int d = threadIdx.x;
    float xv = x[row * DD + d];
    xs[d] = xv;
    float m = waveSum(xv) * (1.0f / 64.0f);
    float c = xv - m;
    float var = waveSum(c * c) * (1.0f / 64.0f);
    float qv = (c / sqrtf(var + 1e-8f)) * g[d] + bln[d];
    qs[d] = qv;
    q[row * DD + d] = qv;
    __syncthreads();
    float aq = bq[d], ak = bk[d], av = bv[d];
#pragma unroll 8
    for (int j = 0; j < DD; ++j) {
        aq += qs[j] * Wq[d * DD + j];
        ak += xs[j] * Wk[d * DD + j];
        av += xs[j] * Wv[d * DD + j];
    }
    Q[row * DD + d] = aq;
    K[row * DD + d] = ak + posK[l * DD + d];
    V[row * DD + d] = av + posV[l * DD + d];
}

// Attention: wave-per-query, lane-per-channel. Block = 4 waves = 4 queries.
// grid = B * (L/4) = 1600 blocks.
// s[q][k] = Qrow . (K_eff[k] + tK[bucket(q,k)]) / sqrt(dh)   (per head)
// out     = sum_k A[h][k] * (V_eff[k] + tV[bucket(q,k)])
__global__ void attn_kernel(const float* __restrict__ Q,
                            const float* __restrict__ Keff,
                            const float* __restrict__ Veff,
                            const int* __restrict__ log_times,
                            const float* __restrict__ tK_emb,
                            const float* __restrict__ tV_emb,
                            float* __restrict__ out) {
    __shared__ int t_s[LLEN];
    __shared__ float sc[4][HH][LLEN];

    int tid = threadIdx.x;
    int wid = tid >> 6;
    int lane = tid & 63;
    int bi = blockIdx.x / (LLEN / 4);
    int qi = (blockIdx.x % (LLEN / 4)) * 4 + wid;
    int row = bi * LLEN + qi;

    if (tid < LLEN) t_s[tid] = log_times[bi * LLEN + tid];
    __syncthreads();

    float qreg = Q[row * DD + lane];
    int tq = t_s[qi];
    int len = qi + 1;
    const float* Kb = Keff + bi * LLEN * DD;
    const float* Vb = Veff + bi * LLEN * DD;

    // phase 1: scores (coalesced row loads, independent iterations)
#pragma unroll 4
    for (int k = 0; k < len; ++k) {
        int dt = tq - t_s[k];
        if (dt < 0) dt = -dt;
        float dtf = fminf((float)dt * (1.0f / 86400.0f), 365.0f);
        int bucket = (int)dtf;   // trunc, matches astype(int32)
        float kv = Kb[k * DD + lane] + tK_emb[bucket * DD + lane];
        float p = qreg * kv;
        p = halfSum(p);          // per-head dot (32 lanes each)
        if ((lane & 31) == 0)
            sc[wid][lane >> 5][k] = p * 0.17677669529663687f;  // 1/sqrt(32)
    }
    __syncthreads();

    // phase 2: softmax — lanes 0..31 head 0, lanes 32..63 head 1
    {
        int h = lane >> 5;
        int kl = lane & 31;
        float m = -INFINITY;
        for (int k = kl; k < len; k += 32) m = fmaxf(m, sc[wid][h][k]);
        m = halfMax(m);
        float s = 0.0f;
        for (int k = kl; k < len; k += 32) {
            float e = expf(sc[wid][h][k] - m);
            sc[wid][h][k] = e;
            s += e;
        }
        s = halfSum(s);
        float inv = 1.0f / s;
        for (int k = kl; k < len; k += 32) sc[wid][h][k] *= inv;
    }
    __syncthreads();

    // phase 3: out[d] = sum_k A[h][k] * (V_eff[k][d] + tV[bucket][d])
    int h = lane >> 5;
    float acc = 0.0f;
#pragma unroll 4
    for (int k = 0; k < len; ++k) {
        int dt = tq - t_s[k];
        if (dt < 0) dt = -dt;
        float dtf = fminf((float)dt * (1.0f / 86400.0f), 365.0f);
        int bucket = (int)dtf;
        float a = sc[wid][h][k];
        acc += a * (Vb[k * DD + lane] + tV_emb[bucket * DD + lane]);
    }
    out[row * DD + lane] = acc;
}

// Fused: x = LN(q+att)*g+b ; x = (x + relu(x@W1^T+b1)@W2^T + b2) * keep
__global__ void addln_ffn_kernel(const float* __restrict__ qin,
                                 const float* __restrict__ att,
                                 const float* __restrict__ g,
                                 const float* __restrict__ bln,
                                 const float* __restrict__ W1, const float* __restrict__ b1,
                                 const float* __restrict__ W2, const float* __restrict__ b2,
                                 const int* __restrict__ log_ids,
                                 float* __restrict__ xout) {
    __shared__ float xs[DD], hs[DD];
    int row = blockIdx.x;
    int d = threadIdx.x;
    float v = qin[row * DD + d] + att[row * DD + d];
    float m = waveSum(v) * (1.0f / 64.0f);
    float c = v - m;
    float var = waveSum(c * c) * (1.0f / 64.0f);
    float xv = (c / sqrtf(var + 1e-8f)) * g[d] + bln[d];
    xs[d] = xv;
    __syncthreads();
    float a = b1[d];
#pragma unroll 8
    for (int j = 0; j < DD; ++j) a += xs[j] * W1[d * DD + j];
    hs[d] = fmaxf(a, 0.0f);
    __syncthreads();
    float o = b2[d];
#pragma unroll 8
    for (int j = 0; j < DD; ++j) o += hs[j] * W2[d * DD + j];
    float res = xv + o;
    if (log_ids[row] == 0) res = 0.0f;
    xout[row * DD + d] = res;
}

// feats = LN(x)*g+b ; pos/neg logits = dot(feats, item_emb[ids])
__global__ void final_kernel(const float* __restrict__ x,
                             const float* __restrict__ g,
                             const float* __restrict__ b,
                             const float* __restrict__ item_emb,
                             const int* __restrict__ pos_ids,
                             const int* __restrict__ neg_ids,
                             float* __restrict__ out) {
    int row = blockIdx.x;
    int d = threadIdx.x;
    float v = x[row * DD + d];
    float m = waveSum(v) * (1.0f / 64.0f);
    float c = v - m;
    float var = waveSum(c * c) * (1.0f / 64.0f);
    float f = (c / sqrtf(var + 1e-8f)) * g[d] + b[d];
    int pid = pos_ids[row];
    int nid = neg_ids[row];
    float p = waveSum(f * item_emb[pid * DD + d]);
    float n = waveSum(f * item_emb[nid * DD + d]);
    if (d == 0) {
        out[row] = p;
        out[BB * LLEN + row] = n;
    }
}

extern "C" void kernel_launch(void* const* d_in, const int* in_sizes, int n_in,
                              void* d_out, int out_size, void* d_ws, size_t ws_size,
                              hipStream_t stream) {
    const int* log_ids = (const int*)d_in[0];
    const int* log_times = (const int*)d_in[1];
    const int* pos_ids = (const int*)d_in[2];
    const int* neg_ids = (const int*)d_in[3];
    const float* item_emb = (const float*)d_in[4];
    const float* posK = (const float*)d_in[5];
    const float* posV = (const float*)d_in[6];
    const float* tK_emb = (const float*)d_in[7];
    const float* tV_emb = (const float*)d_in[8];
    const float* ln1_g = (const float*)d_in[9];
    const float* ln1_b = (const float*)d_in[10];
    const float* Wq = (const float*)d_in[11];
    const float* bq = (const float*)d_in[12];
    const float* Wk = (const float*)d_in[13];
    const float* bk = (const float*)d_in[14];
    const float* Wv = (const float*)d_in[15];
    const float* bv = (const float*)d_in[16];
    const float* ln2_g = (const float*)d_in[17];
    const float* ln2_b = (const float*)d_in[18];
    const float* W1 = (const float*)d_in[19];
    const float* b1 = (const float*)d_in[20];
    const float* W2 = (const float*)d_in[21];
    const float* b2 = (const float*)d_in[22];
    const float* lnf_g = (const float*)d_in[23];
    const float* lnf_b = (const float*)d_in[24];

    float* ws = (float*)d_ws;
    float* x = ws;                 // [B,L,D]
    float* q = x + BLD;            // ln1 output (kept for residual)
    float* Qb = q + BLD;
    float* Kb = Qb + BLD;
    float* Vb = Kb + BLD;
    float* att = Vb + BLD;

    const int nrow = BB * LLEN;    // 6400

    embed_kernel<<<nrow, DD, 0, stream>>>(log_ids, item_emb, x);

    for (int i = 0; i < NLAYER; ++i) {
        ln_qkv_kernel<<<nrow, DD, 0, stream>>>(x, ln1_g + i * DD, ln1_b + i * DD,
                                               Wq + i * DD * DD, bq + i * DD,
                                               Wk + i * DD * DD, bk + i * DD,
                                               Wv + i * DD * DD, bv + i * DD,
                                               posK, posV,
                                               q, Qb, Kb, Vb);
        attn_kernel<<<BB * (LLEN / 4), 256, 0, stream>>>(Qb, Kb, Vb, log_times,
                                                         tK_emb, tV_emb, att);
        addln_ffn_kernel<<<nrow, DD, 0, stream>>>(q, att, ln2_g + i * DD,
                                                  ln2_b + i * DD,
                                                  W1 + i * DD * DD, b1 + i * DD,
                                                  W2 + i * DD * DD, b2 + i * DD,
                                                  log_ids, x);
    }

    final_kernel<<<nrow, DD, 0, stream>>>(x, lnf_g, lnf_b, item_emb,
                                          pos_ids, neg_ids, (float*)d_out);
}

// Round 4
// 292.302 us; speedup vs baseline: 3.5154x; 1.2888x over previous
//
#include <hip/hip_runtime.h>
#include <math.h>

// TiSASRec forward on MI355X — round 3:
//  - attn: balanced block composition {i,99-i,100+i,199-i}, no inter-phase
//    barriers (per-wave phases), 4-accumulator ILP in PV phase.
//  - weights transposed once into ws -> coalesced W reads in ln_qkv/ffn.
// B=32, L=200, D=64, H=2, dh=32, NL=2.
#define BB 32
#define LLEN 200
#define DD 64
#define HH 2
#define DHH 32
#define NLAYER 2
#define BLD (BB * LLEN * DD)

__device__ inline float waveSum(float v) {
#pragma unroll
    for (int off = 32; off > 0; off >>= 1) v += __shfl_xor(v, off);
    return v;
}
// reduce within each 32-lane half (per-head)
__device__ inline float halfSum(float v) {
    v += __shfl_xor(v, 1);
    v += __shfl_xor(v, 2);
    v += __shfl_xor(v, 4);
    v += __shfl_xor(v, 8);
    v += __shfl_xor(v, 16);
    return v;
}
__device__ inline float halfMax(float v) {
    v = fmaxf(v, __shfl_xor(v, 1));
    v = fmaxf(v, __shfl_xor(v, 2));
    v = fmaxf(v, __shfl_xor(v, 4));
    v = fmaxf(v, __shfl_xor(v, 8));
    v = fmaxf(v, __shfl_xor(v, 16));
    return v;
}

// Transpose the 10 64x64 weight matrices into ws (one launch, grid=10).
// m = layer*5 + {0:Wq,1:Wk,2:Wv,3:W1,4:W2}; dst[m] is W^T (64x64).
__global__ void transposeW_kernel(const float* __restrict__ Wq,
                                  const float* __restrict__ Wk,
                                  const float* __restrict__ Wv,
                                  const float* __restrict__ W1,
                                  const float* __restrict__ W2,
                                  float* __restrict__ out) {
    int m = blockIdx.x;
    const float* src;
    switch (m % 5) {
        case 0: src = Wq; break;
        case 1: src = Wk; break;
        case 2: src = Wv; break;
        case 3: src = W1; break;
        default: src = W2; break;
    }
    src += (m / 5) * DD * DD;
    float* dst = out + m * DD * DD;
    for (int e = threadIdx.x; e < DD * DD; e += 256) {
        int d = e >> 6, j = e & 63;
        dst[j * DD + d] = src[e];
    }
}

// x[b,l,:] = item_emb[log_ids[b,l]] * sqrt(D) * keep
__global__ void embed_kernel(const int* __restrict__ log_ids,
                             const float* __restrict__ item_emb,
                             float* __restrict__ x) {
    int row = blockIdx.x;
    int d = threadIdx.x;
    int id = log_ids[row];
    float v = item_emb[id * DD + d] * 8.0f;  // sqrt(64)
    x[row * DD + d] = (id == 0) ? 0.0f : v;
}

// Fused: q = LN(x)*g+b (kept for residual), then (transposed-weight matmuls)
// Q = q@Wq^T+bq ; K_eff = x@Wk^T+bk+posK[l] ; V_eff = x@Wv^T+bv+posV[l].
__global__ void ln_qkv_kernel(const float* __restrict__ x,
                              const float* __restrict__ g,
                              const float* __restrict__ bln,
                              const float* __restrict__ WqT, const float* __restrict__ bq,
                              const float* __restrict__ WkT, const float* __restrict__ bk,
                              const float* __restrict__ WvT, const float* __restrict__ bv,
                              const float* __restrict__ posK,
                              const float* __restrict__ posV,
                              float* __restrict__ q,
                              float* __restrict__ Q, float* __restrict__ K,
                              float* __restrict__ V) {
    __shared__ float qs[DD], xs[DD];
    int row = blockIdx.x;
    int l = row % LLEN;
    int d = threadIdx.x;
    float xv = x[row * DD + d];
    xs[d] = xv;
    float m = waveSum(xv) * (1.0f / 64.0f);
    float c = xv - m;
    float var = waveSum(c * c) * (1.0f / 64.0f);
    float qv = (c / sqrtf(var + 1e-8f)) * g[d] + bln[d];
    qs[d] = qv;
    q[row * DD + d] = qv;
    __syncthreads();
    float aq = bq[d], ak = bk[d], av = bv[d];
#pragma unroll 8
    for (int j = 0; j < DD; ++j) {
        aq = fmaf(qs[j], WqT[j * DD + d], aq);
        ak = fmaf(xs[j], WkT[j * DD + d], ak);
        av = fmaf(xs[j], WvT[j * DD + d], av);
    }
    Q[row * DD + d] = aq;
    K[row * DD + d] = ak + posK[l * DD + d];
    V[row * DD + d] = av + posV[l * DD + d];
}

// Attention: wave-per-query, lane-per-channel. Block = 4 waves with queries
// {i, 99-i, 100+i, 199-i} (balanced). No inter-phase barriers.
__global__ void attn_kernel(const float* __restrict__ Q,
                            const float* __restrict__ Keff,
                            const float* __restrict__ Veff,
                            const int* __restrict__ log_times,
                            const float* __restrict__ tK_emb,
                            const float* __restrict__ tV_emb,
                            float* __restrict__ out) {
    __shared__ int t_s[LLEN];
    __shared__ float sc[4][HH][LLEN];

    int tid = threadIdx.x;
    int wid = tid >> 6;
    int lane = tid & 63;
    int bi = blockIdx.x / 50;
    int i = blockIdx.x % 50;
    int qi = (wid == 0) ? i : (wid == 1) ? (99 - i) : (wid == 2) ? (100 + i) : (199 - i);
    int row = bi * LLEN + qi;

    if (tid < LLEN) t_s[tid] = log_times[bi * LLEN + tid];
    __syncthreads();

    float qreg = Q[row * DD + lane];
    int tq = t_s[qi];
    int len = qi + 1;
    const float* Kb = Keff + bi * LLEN * DD + lane;
    const float* Vb = Veff + bi * LLEN * DD + lane;
    const float* tKl = tK_emb + lane;
    const float* tVl = tV_emb + lane;

    // phase 1: scores. s = Q . (K_eff + tK[bucket]) / sqrt(dh), per head.
#pragma unroll 4
    for (int k = 0; k < len; ++k) {
        int dt = tq - t_s[k];
        if (dt < 0) dt = -dt;
        float dtf = fminf((float)dt * (1.0f / 86400.0f), 365.0f);
        int bucket = (int)dtf;   // trunc, matches astype(int32)
        float kv = Kb[k * DD] + tKl[bucket * DD];
        float p = halfSum(qreg * kv) * 0.17677669529663687f;  // 1/sqrt(32)
        if ((lane & 31) == 0) sc[wid][lane >> 5][k] = p;
    }

    // phase 2: softmax — lanes 0..31 head 0, lanes 32..63 head 1 (same wave)
    {
        int h = lane >> 5;
        int kl = lane & 31;
        float m = -INFINITY;
        for (int k = kl; k < len; k += 32) m = fmaxf(m, sc[wid][h][k]);
        m = halfMax(m);
        float s = 0.0f;
        for (int k = kl; k < len; k += 32) {
            float e = expf(sc[wid][h][k] - m);
            sc[wid][h][k] = e;
            s += e;
        }
        s = halfSum(s);
        float inv = 1.0f / s;
        for (int k = kl; k < len; k += 32) sc[wid][h][k] *= inv;
    }

    // phase 3: out[d] = sum_k A[h][k] * (V_eff[k][d] + tV[bucket][d])
    int h = lane >> 5;
    float acc0 = 0.0f, acc1 = 0.0f, acc2 = 0.0f, acc3 = 0.0f;
    int k = 0;
    for (; k + 4 <= len; k += 4) {
        int dt0 = tq - t_s[k + 0]; if (dt0 < 0) dt0 = -dt0;
        int dt1 = tq - t_s[k + 1]; if (dt1 < 0) dt1 = -dt1;
        int dt2 = tq - t_s[k + 2]; if (dt2 < 0) dt2 = -dt2;
        int dt3 = tq - t_s[k + 3]; if (dt3 < 0) dt3 = -dt3;
        int b0 = (int)fminf((float)dt0 * (1.0f / 86400.0f), 365.0f);
        int b1 = (int)fminf((float)dt1 * (1.0f / 86400.0f), 365.0f);
        int b2 = (int)fminf((float)dt2 * (1.0f / 86400.0f), 365.0f);
        int b3 = (int)fminf((float)dt3 * (1.0f / 86400.0f), 365.0f);
        float a0 = sc[wid][h][k + 0];
        float a1 = sc[wid][h][k + 1];
        float a2 = sc[wid][h][k + 2];
        float a3 = sc[wid][h][k + 3];
        acc0 = fmaf(a0, Vb[(k + 0) * DD] + tVl[b0 * DD], acc0);
        acc1 = fmaf(a1, Vb[(k + 1) * DD] + tVl[b1 * DD], acc1);
        acc2 = fmaf(a2, Vb[(k + 2) * DD] + tVl[b2 * DD], acc2);
        acc3 = fmaf(a3, Vb[(k + 3) * DD] + tVl[b3 * DD], acc3);
    }
    for (; k < len; ++k) {
        int dt = tq - t_s[k]; if (dt < 0) dt = -dt;
        int b0 = (int)fminf((float)dt * (1.0f / 86400.0f), 365.0f);
        acc0 = fmaf(sc[wid][h][k], Vb[k * DD] + tVl[b0 * DD], acc0);
    }
    out[row * DD + lane] = (acc0 + acc1) + (acc2 + acc3);
}

// Fused: x = LN(q+att)*g+b ; x = (x + relu(x@W1^T+b1)@W2^T + b2) * keep
__global__ void addln_ffn_kernel(const float* __restrict__ qin,
                                 const float* __restrict__ att,
                                 const float* __restrict__ g,
                                 const float* __restrict__ bln,
                                 const float* __restrict__ W1T, const float* __restrict__ b1,
                                 const float* __restrict__ W2T, const float* __restrict__ b2,
                                 const int* __restrict__ log_ids,
                                 float* __restrict__ xout) {
    __shared__ float xs[DD], hs[DD];
    int row = blockIdx.x;
    int d = threadIdx.x;
    float v = qin[row * DD + d] + att[row * DD + d];
    float m = waveSum(v) * (1.0f / 64.0f);
    float c = v - m;
    float var = waveSum(c * c) * (1.0f / 64.0f);
    float xv = (c / sqrtf(var + 1e-8f)) * g[d] + bln[d];
    xs[d] = xv;
    __syncthreads();
    float a = b1[d];
#pragma unroll 8
    for (int j = 0; j < DD; ++j) a = fmaf(xs[j], W1T[j * DD + d], a);
    hs[d] = fmaxf(a, 0.0f);
    __syncthreads();
    float o = b2[d];
#pragma unroll 8
    for (int j = 0; j < DD; ++j) o = fmaf(hs[j], W2T[j * DD + d], o);
    float res = xv + o;
    if (log_ids[row] == 0) res = 0.0f;
    xout[row * DD + d] = res;
}

// feats = LN(x)*g+b ; pos/neg logits = dot(feats, item_emb[ids])
__global__ void final_kernel(const float* __restrict__ x,
                             const float* __restrict__ g,
                             const float* __restrict__ b,
                             const float* __restrict__ item_emb,
                             const int* __restrict__ pos_ids,
                             const int* __restrict__ neg_ids,
                             float* __restrict__ out) {
    int row = blockIdx.x;
    int d = threadIdx.x;
    float v = x[row * DD + d];
    float m = waveSum(v) * (1.0f / 64.0f);
    float c = v - m;
    float var = waveSum(c * c) * (1.0f / 64.0f);
    float f = (c / sqrtf(var + 1e-8f)) * g[d] + b[d];
    int pid = pos_ids[row];
    int nid = neg_ids[row];
    float p = waveSum(f * item_emb[pid * DD + d]);
    float n = waveSum(f * item_emb[nid * DD + d]);
    if (d == 0) {
        out[row] = p;
        out[BB * LLEN + row] = n;
    }
}

extern "C" void kernel_launch(void* const* d_in, const int* in_sizes, int n_in,
                              void* d_out, int out_size, void* d_ws, size_t ws_size,
                              hipStream_t stream) {
    const int* log_ids = (const int*)d_in[0];
    const int* log_times = (const int*)d_in[1];
    const int* pos_ids = (const int*)d_in[2];
    const int* neg_ids = (const int*)d_in[3];
    const float* item_emb = (const float*)d_in[4];
    const float* posK = (const float*)d_in[5];
    const float* posV = (const float*)d_in[6];
    const float* tK_emb = (const float*)d_in[7];
    const float* tV_emb = (const float*)d_in[8];
    const float* ln1_g = (const float*)d_in[9];
    const float* ln1_b = (const float*)d_in[10];
    const float* Wq = (const float*)d_in[11];
    const float* bq = (const float*)d_in[12];
    const float* Wk = (const float*)d_in[13];
    const float* bk = (const float*)d_in[14];
    const float* Wv = (const float*)d_in[15];
    const float* bv = (const float*)d_in[16];
    const float* ln2_g = (const float*)d_in[17];
    const float* ln2_b = (const float*)d_in[18];
    const float* W1 = (const float*)d_in[19];
    const float* b1 = (const float*)d_in[20];
    const float* W2 = (const float*)d_in[21];
    const float* b2 = (const float*)d_in[22];
    const float* lnf_g = (const float*)d_in[23];
    const float* lnf_b = (const float*)d_in[24];

    float* ws = (float*)d_ws;
    float* x = ws;                 // [B,L,D]
    float* q = x + BLD;            // ln1 output (kept for residual)
    float* Qb = q + BLD;
    float* Kb = Qb + BLD;
    float* Vb = Kb + BLD;
    float* att = Vb + BLD;
    float* wt = att + BLD;         // 10 transposed 64x64 weight matrices

    const int nrow = BB * LLEN;    // 6400

    transposeW_kernel<<<10, 256, 0, stream>>>(Wq, Wk, Wv, W1, W2, wt);
    embed_kernel<<<nrow, DD, 0, stream>>>(log_ids, item_emb, x);

    for (int i = 0; i < NLAYER; ++i) {
        const float* WqT = wt + (i * 5 + 0) * DD * DD;
        const float* WkT = wt + (i * 5 + 1) * DD * DD;
        const float* WvT = wt + (i * 5 + 2) * DD * DD;
        const float* W1T = wt + (i * 5 + 3) * DD * DD;
        const float* W2T = wt + (i * 5 + 4) * DD * DD;
        ln_qkv_kernel<<<nrow, DD, 0, stream>>>(x, ln1_g + i * DD, ln1_b + i * DD,
                                               WqT, bq + i * DD,
                                               WkT, bk + i * DD,
                                               WvT, bv + i * DD,
                                               posK, posV,
                                               q, Qb, Kb, Vb);
        attn_kernel<<<BB * 50, 256, 0, stream>>>(Qb, Kb, Vb, log_times,
                                                 tK_emb, tV_emb, att);
        addln_ffn_kernel<<<nrow, DD, 0, stream>>>(q, att, ln2_g + i * DD,
                                                  ln2_b + i * DD,
                                                  W1T, b1 + i * DD,
                                                  W2T, b2 + i * DD,
                                                  log_ids, x);
    }

    final_kernel<<<nrow, DD, 0, stream>>>(x, lnf_g, lnf_b, item_emb,
                                          pos_ids, neg_ids, (float*)d_out);
}

// Round 5
// 196.897 us; speedup vs baseline: 5.2188x; 1.4845x over previous
//
#include <hip/hip_runtime.h>
#include <math.h>

// TiSASRec forward on MI355X — round 4:
//  - Qt table (Q @ tK_emb^T) kills per-(q,k) tK row reads
//  - 4-key-group score phase: float4 K loads, 3-shfl reduce per 4 keys
//  - buckets cached in LDS (tm_s), reused by PV phase
//  - 4-row blocks for ln_qkv / addln_ffn / embed / final
// B=32, L=200, D=64, H=2, dh=32, NL=2.
#define BB 32
#define LLEN 200
#define DD 64
#define HH 2
#define NLAYER 2
#define BLD (BB * LLEN * DD)
#define TSPAN1 366   // TIME_SPAN+1

__device__ inline float waveSum(float v) {
#pragma unroll
    for (int off = 32; off > 0; off >>= 1) v += __shfl_xor(v, off);
    return v;
}
__device__ inline float halfSum(float v) {
    v += __shfl_xor(v, 1);
    v += __shfl_xor(v, 2);
    v += __shfl_xor(v, 4);
    v += __shfl_xor(v, 8);
    v += __shfl_xor(v, 16);
    return v;
}
__device__ inline float halfMax(float v) {
    v = fmaxf(v, __shfl_xor(v, 1));
    v = fmaxf(v, __shfl_xor(v, 2));
    v = fmaxf(v, __shfl_xor(v, 4));
    v = fmaxf(v, __shfl_xor(v, 8));
    v = fmaxf(v, __shfl_xor(v, 16));
    return v;
}

// grid=11: m<10 -> transpose 64x64 weights; m==10 -> transpose tK_emb to [64][366]
__global__ void transpose_kernel(const float* __restrict__ Wq,
                                 const float* __restrict__ Wk,
                                 const float* __restrict__ Wv,
                                 const float* __restrict__ W1,
                                 const float* __restrict__ W2,
                                 const float* __restrict__ tK_emb,
                                 float* __restrict__ wt,
                                 float* __restrict__ tKT) {
    int m = blockIdx.x;
    if (m < 10) {
        const float* src;
        switch (m % 5) {
            case 0: src = Wq; break;
            case 1: src = Wk; break;
            case 2: src = Wv; break;
            case 3: src = W1; break;
            default: src = W2; break;
        }
        src += (m / 5) * DD * DD;
        float* dst = wt + m * DD * DD;
        for (int e = threadIdx.x; e < DD * DD; e += 256) {
            int d = e >> 6, j = e & 63;
            dst[j * DD + d] = src[e];
        }
    } else {
        for (int e = threadIdx.x; e < TSPAN1 * DD; e += 256) {
            int t = e >> 6, d = e & 63;
            tKT[d * TSPAN1 + t] = tK_emb[e];
        }
    }
}

// 4 rows per block: x[row,:] = item_emb[log_ids[row]] * 8 * keep
__global__ void embed_kernel(const int* __restrict__ log_ids,
                             const float* __restrict__ item_emb,
                             float* __restrict__ x) {
    int tid = threadIdx.x;
    int row = blockIdx.x * 4 + (tid >> 6);
    int d = tid & 63;
    int id = log_ids[row];
    float v = item_emb[id * DD + d] * 8.0f;
    x[row * DD + d] = (id == 0) ? 0.0f : v;
}

// 4 rows/block, wave per row. q=LN(x); Q=q@WqT+bq; K=x@WkT+bk+posK; V likewise.
__global__ void ln_qkv_kernel(const float* __restrict__ x,
                              const float* __restrict__ g,
                              const float* __restrict__ bln,
                              const float* __restrict__ WqT, const float* __restrict__ bq,
                              const float* __restrict__ WkT, const float* __restrict__ bk,
                              const float* __restrict__ WvT, const float* __restrict__ bv,
                              const float* __restrict__ posK,
                              const float* __restrict__ posV,
                              float* __restrict__ q,
                              float* __restrict__ Q, float* __restrict__ K,
                              float* __restrict__ V) {
    __shared__ float qs[4][DD], xs[4][DD];
    int tid = threadIdx.x;
    int wid = tid >> 6, d = tid & 63;
    int row = blockIdx.x * 4 + wid;
    int l = row % LLEN;
    float xv = x[row * DD + d];
    xs[wid][d] = xv;
    float m = waveSum(xv) * (1.0f / 64.0f);
    float c = xv - m;
    float var = waveSum(c * c) * (1.0f / 64.0f);
    float qv = (c / sqrtf(var + 1e-8f)) * g[d] + bln[d];
    qs[wid][d] = qv;
    q[row * DD + d] = qv;
    // per-wave LDS region; wave-lockstep + compiler lgkmcnt makes this safe
    float aq = bq[d], ak = bk[d], av = bv[d];
#pragma unroll 8
    for (int j = 0; j < DD; ++j) {
        aq = fmaf(qs[wid][j], WqT[j * DD + d], aq);
        ak = fmaf(xs[wid][j], WkT[j * DD + d], ak);
        av = fmaf(xs[wid][j], WvT[j * DD + d], av);
    }
    Q[row * DD + d] = aq;
    K[row * DD + d] = ak + posK[l * DD + d];
    V[row * DD + d] = av + posV[l * DD + d];
}

// Qt[row][h][t] = sum_d Qh[row][h*32+d] * tK_emb[t][h*32+d]
// 8 rows per block, 384 threads (thread t<366 owns one t).
__global__ void qt_kernel(const float* __restrict__ Q,
                          const float* __restrict__ tKT,
                          float* __restrict__ Qt_g) {
    __shared__ float Qs[8][DD];
    int tid = threadIdx.x;
    int base = blockIdx.x * 8;
    for (int e = tid; e < 8 * DD; e += 384)
        Qs[e >> 6][e & 63] = Q[(base + (e >> 6)) * DD + (e & 63)];
    __syncthreads();
    int t = tid;
    if (t < TSPAN1) {
        float accA[8] = {0, 0, 0, 0, 0, 0, 0, 0};
        float accB[8] = {0, 0, 0, 0, 0, 0, 0, 0};
        for (int d = 0; d < 32; ++d) {
            float v = tKT[d * TSPAN1 + t];
#pragma unroll
            for (int gg = 0; gg < 8; ++gg) accA[gg] = fmaf(v, Qs[gg][d], accA[gg]);
        }
        for (int d = 32; d < 64; ++d) {
            float v = tKT[d * TSPAN1 + t];
#pragma unroll
            for (int gg = 0; gg < 8; ++gg) accB[gg] = fmaf(v, Qs[gg][d], accB[gg]);
        }
#pragma unroll
        for (int gg = 0; gg < 8; ++gg) {
            Qt_g[(base + gg) * (2 * TSPAN1) + t] = accA[gg];
            Qt_g[(base + gg) * (2 * TSPAN1) + TSPAN1 + t] = accB[gg];
        }
    }
}

// Attention: wave-per-query {i,99-i,100+i,199-i}. Phases are per-wave (no
// inter-phase barriers). Phase 1 uses 4-key groups: half = head, lanes =
// 8 chunks x 4 keys; float4 K loads; 3-shfl chunk reduce; Qt LDS lookup.
__global__ void attn_kernel(const float* __restrict__ Q,
                            const float* __restrict__ Keff,
                            const float* __restrict__ Veff,
                            const int* __restrict__ log_times,
                            const float* __restrict__ Qt_g,
                            const float* __restrict__ tV_emb,
                            float* __restrict__ out) {
    __shared__ int t_s[LLEN];
    __shared__ float sc[4][HH][LLEN];
    __shared__ unsigned short tm_s[4][LLEN];
    __shared__ float qt_s[4][2 * TSPAN1];

    int tid = threadIdx.x;
    int wid = tid >> 6;
    int lane = tid & 63;
    int bi = blockIdx.x / 50;
    int i = blockIdx.x % 50;
    int qi = (wid == 0) ? i : (wid == 1) ? (99 - i) : (wid == 2) ? (100 + i) : (199 - i);
    int row = bi * LLEN + qi;
    int len = qi + 1;

    if (tid < LLEN) t_s[tid] = log_times[bi * LLEN + tid];
    __syncthreads();

    // stage this query's Qt row (732 floats) into LDS
    const float* qtrow = Qt_g + row * (2 * TSPAN1);
    for (int e = lane; e < 2 * TSPAN1; e += 64) qt_s[wid][e] = qtrow[e];

    // build bucket table for this query
    int tq = t_s[qi];
    for (int k = lane; k < len; k += 64) {
        int dt = tq - t_s[k];
        if (dt < 0) dt = -dt;
        float dtf = fminf((float)dt * (1.0f / 86400.0f), 365.0f);
        tm_s[wid][k] = (unsigned short)(int)dtf;
    }

    int h = lane >> 5;       // head
    int l5 = lane & 31;
    int cch = l5 >> 2;       // channel chunk 0..7
    int j = l5 & 3;          // key offset in group
    float4 qv = ((const float4*)(Q + row * DD))[h * 8 + cch];
    const float4* K4 = (const float4*)(Keff + bi * LLEN * DD);
    const float scale = 0.17677669529663687f;  // 1/sqrt(32)

    // phase 1: scores, 4 keys per iteration
    for (int k0 = 0; k0 < len; k0 += 4) {
        int k = k0 + j;
        int kc = (k < len) ? k : (len - 1);
        int bucket = tm_s[wid][kc];
        float4 kv = K4[kc * 16 + h * 8 + cch];
        float p = qv.x * kv.x + qv.y * kv.y + qv.z * kv.z + qv.w * kv.w;
        p += __shfl_xor(p, 4);
        p += __shfl_xor(p, 8);
        p += __shfl_xor(p, 16);   // p = full 32-dot for (h, key k)
        float s = (p + qt_s[wid][h * TSPAN1 + bucket]) * scale;
        if (cch == 0 && k < len) sc[wid][h][k] = s;
    }

    // phase 2: softmax (lanes 0..31 head 0, 32..63 head 1; same wave)
    {
        int kl = l5;
        float m = -INFINITY;
        for (int k = kl; k < len; k += 32) m = fmaxf(m, sc[wid][h][k]);
        m = halfMax(m);
        float s = 0.0f;
        for (int k = kl; k < len; k += 32) {
            float e = expf(sc[wid][h][k] - m);
            sc[wid][h][k] = e;
            s += e;
        }
        s = halfSum(s);
        float inv = 1.0f / s;
        for (int k = kl; k < len; k += 32) sc[wid][h][k] *= inv;
    }

    // phase 3: out[d] = sum_k A[h][k] * (V_eff[k][d] + tV[bucket[k]][d])
    const float* Vb = Veff + bi * LLEN * DD + lane;
    const float* tVl = tV_emb + lane;
    float acc0 = 0.0f, acc1 = 0.0f, acc2 = 0.0f, acc3 = 0.0f;
    int k = 0;
    for (; k + 4 <= len; k += 4) {
        int b0 = tm_s[wid][k + 0];
        int b1 = tm_s[wid][k + 1];
        int b2 = tm_s[wid][k + 2];
        int b3 = tm_s[wid][k + 3];
        float a0 = sc[wid][h][k + 0];
        float a1 = sc[wid][h][k + 1];
        float a2 = sc[wid][h][k + 2];
        float a3 = sc[wid][h][k + 3];
        acc0 = fmaf(a0, Vb[(k + 0) * DD] + tVl[b0 * DD], acc0);
        acc1 = fmaf(a1, Vb[(k + 1) * DD] + tVl[b1 * DD], acc1);
        acc2 = fmaf(a2, Vb[(k + 2) * DD] + tVl[b2 * DD], acc2);
        acc3 = fmaf(a3, Vb[(k + 3) * DD] + tVl[b3 * DD], acc3);
    }
    for (; k < len; ++k) {
        int b0 = tm_s[wid][k];
        acc0 = fmaf(sc[wid][h][k], Vb[k * DD] + tVl[b0 * DD], acc0);
    }
    out[row * DD + lane] = (acc0 + acc1) + (acc2 + acc3);
}

// 4 rows/block: x = LN(q+att); x = (x + relu(x@W1T+b1)@W2T + b2) * keep
__global__ void addln_ffn_kernel(const float* __restrict__ qin,
                                 const float* __restrict__ att,
                                 const float* __restrict__ g,
                                 const float* __restrict__ bln,
                                 const float* __restrict__ W1T, const float* __restrict__ b1,
                                 const float* __restrict__ W2T, const float* __restrict__ b2,
                                 const int* __restrict__ log_ids,
                                 float* __restrict__ xout) {
    __shared__ float xs[4][DD], hs[4][DD];
    int tid = threadIdx.x;
    int wid = tid >> 6, d = tid & 63;
    int row = blockIdx.x * 4 + wid;
    float v = qin[row * DD + d] + att[row * DD + d];
    float m = waveSum(v) * (1.0f / 64.0f);
    float c = v - m;
    float var = waveSum(c * c) * (1.0f / 64.0f);
    float xv = (c / sqrtf(var + 1e-8f)) * g[d] + bln[d];
    xs[wid][d] = xv;
    float a = b1[d];
#pragma unroll 8
    for (int j = 0; j < DD; ++j) a = fmaf(xs[wid][j], W1T[j * DD + d], a);
    hs[wid][d] = fmaxf(a, 0.0f);
    float o = b2[d];
#pragma unroll 8
    for (int j = 0; j < DD; ++j) o = fmaf(hs[wid][j], W2T[j * DD + d], o);
    float res = xv + o;
    if (log_ids[row] == 0) res = 0.0f;
    xout[row * DD + d] = res;
}

// 4 rows/block: feats = LN(x); logits = dot(feats, item_emb[pos/neg])
__global__ void final_kernel(const float* __restrict__ x,
                             const float* __restrict__ g,
                             const float* __restrict__ b,
                             const float* __restrict__ item_emb,
                             const int* __restrict__ pos_ids,
                             const int* __restrict__ neg_ids,
                             float* __restrict__ out) {
    int tid = threadIdx.x;
    int wid = tid >> 6, d = tid & 63;
    int row = blockIdx.x * 4 + wid;
    float v = x[row * DD + d];
    float m = waveSum(v) * (1.0f / 64.0f);
    float c = v - m;
    float var = waveSum(c * c) * (1.0f / 64.0f);
    float f = (c / sqrtf(var + 1e-8f)) * g[d] + b[d];
    int pid = pos_ids[row];
    int nid = neg_ids[row];
    float p = waveSum(f * item_emb[pid * DD + d]);
    float n = waveSum(f * item_emb[nid * DD + d]);
    if (d == 0) {
        out[row] = p;
        out[BB * LLEN + row] = n;
    }
}

extern "C" void kernel_launch(void* const* d_in, const int* in_sizes, int n_in,
                              void* d_out, int out_size, void* d_ws, size_t ws_size,
                              hipStream_t stream) {
    const int* log_ids = (const int*)d_in[0];
    const int* log_times = (const int*)d_in[1];
    const int* pos_ids = (const int*)d_in[2];
    const int* neg_ids = (const int*)d_in[3];
    const float* item_emb = (const float*)d_in[4];
    const float* posK = (const float*)d_in[5];
    const float* posV = (const float*)d_in[6];
    const float* tK_emb = (const float*)d_in[7];
    const float* tV_emb = (const float*)d_in[8];
    const float* ln1_g = (const float*)d_in[9];
    const float* ln1_b = (const float*)d_in[10];
    const float* Wq = (const float*)d_in[11];
    const float* bq = (const float*)d_in[12];
    const float* Wk = (const float*)d_in[13];
    const float* bk = (const float*)d_in[14];
    const float* Wv = (const float*)d_in[15];
    const float* bv = (const float*)d_in[16];
    const float* ln2_g = (const float*)d_in[17];
    const float* ln2_b = (const float*)d_in[18];
    const float* W1 = (const float*)d_in[19];
    const float* b1 = (const float*)d_in[20];
    const float* W2 = (const float*)d_in[21];
    const float* b2 = (const float*)d_in[22];
    const float* lnf_g = (const float*)d_in[23];
    const float* lnf_b = (const float*)d_in[24];

    float* ws = (float*)d_ws;
    float* x = ws;                        // [B,L,D]
    float* q = x + BLD;
    float* Qb = q + BLD;
    float* Kb = Qb + BLD;
    float* Vb = Kb + BLD;
    float* att = Vb + BLD;
    float* wt = att + BLD;                // 10 x 64x64 transposed weights
    float* tKT = wt + 10 * DD * DD;       // [64][366]
    float* Qt = tKT + DD * TSPAN1;        // [6400][732]

    const int nrow = BB * LLEN;           // 6400

    transpose_kernel<<<11, 256, 0, stream>>>(Wq, Wk, Wv, W1, W2, tK_emb, wt, tKT);
    embed_kernel<<<nrow / 4, 256, 0, stream>>>(log_ids, item_emb, x);

    for (int i = 0; i < NLAYER; ++i) {
        const float* WqT = wt + (i * 5 + 0) * DD * DD;
        const float* WkT = wt + (i * 5 + 1) * DD * DD;
        const float* WvT = wt + (i * 5 + 2) * DD * DD;
        const float* W1T = wt + (i * 5 + 3) * DD * DD;
        const float* W2T = wt + (i * 5 + 4) * DD * DD;
        ln_qkv_kernel<<<nrow / 4, 256, 0, stream>>>(x, ln1_g + i * DD, ln1_b + i * DD,
                                                    WqT, bq + i * DD,
                                                    WkT, bk + i * DD,
                                                    WvT, bv + i * DD,
                                                    posK, posV,
                                                    q, Qb, Kb, Vb);
        qt_kernel<<<nrow / 8, 384, 0, stream>>>(Qb, tKT, Qt);
        attn_kernel<<<BB * 50, 256, 0, stream>>>(Qb, Kb, Vb, log_times,
                                                 Qt, tV_emb, att);
        addln_ffn_kernel<<<nrow / 4, 256, 0, stream>>>(q, att, ln2_g + i * DD,
                                                       ln2_b + i * DD,
                                                       W1T, b1 + i * DD,
                                                       W2T, b2 + i * DD,
                                                       log_ids, x);
    }

    final_kernel<<<nrow / 4, 256, 0, stream>>>(x, lnf_g, lnf_b, item_emb,
                                               pos_ids, neg_ids, (float*)d_out);
}